// Round 4
// baseline (459.883 us; speedup 1.0000x reference)
//
#include <hip/hip_runtime.h>

// Problem constants
#define N_ROWS 16384   // B*T
#define C_DIM  1024
#define GV     640     // G*V
#define V_DIM  320
#define G_DIM  2
#define D_DIM  256
#define MROWS  64      // rows per fused block
#define FBLKS  (N_ROWS / MROWS)  // 256 = exactly 1 block/CU
#define NBUCKET 64

typedef __attribute__((ext_vector_type(8))) _Float16 half8;
typedef __attribute__((ext_vector_type(4))) _Float16 half4v;
typedef __attribute__((ext_vector_type(4))) float float4v;

#define LDS_AS(p) ((__attribute__((address_space(3))) unsigned int*)(p))
#define GLB_AS(p) ((const __attribute__((address_space(1))) unsigned int*)(p))

// ---------------- W -> fp16 hi, pre-swizzled into 16B-chunk-transposed layout ----
// whT[((kb*4 + c)*640 + n)*8 + h] = (half)W[n][kb*32 + c*8 + h]
// Also zeroes the mf/mi atomic-partial region (81,920 threads x 4 B = 327,680 B).
__global__ __launch_bounds__(256) void wsplit_kernel(const float* __restrict__ src,
                                                     _Float16* __restrict__ dst,
                                                     int* __restrict__ zr) {
  const int t = blockIdx.x * 256 + threadIdx.x;  // 0..81919
  zr[t] = 0;
  const int n = t % GV;
  const int cc = t / GV;       // 0..127 ; k = cc*8
  const int k = cc * 8;
  const float4 v0 = *(const float4*)(src + (size_t)n * C_DIM + k);
  const float4 v1 = *(const float4*)(src + (size_t)n * C_DIM + k + 4);
  half8 h;
  h[0] = (_Float16)v0.x; h[1] = (_Float16)v0.y; h[2] = (_Float16)v0.z; h[3] = (_Float16)v0.w;
  h[4] = (_Float16)v1.x; h[5] = (_Float16)v1.y; h[6] = (_Float16)v1.z; h[7] = (_Float16)v1.w;
  *(half8*)(dst + (size_t)t * 8) = h;
}

// ---------------- Fused: GEMM (M=64 x N=640 per block) + transposed epilogue ----
// GEMM loop identical to the round-1/2 version (double-buffered, 1 barrier/iter).
// Epilogue rewritten: 4 phases (2 groups x 2 row-halves of 32 rows). Per phase,
// each row is handled by 16 lanes scanning 20 values each:
//   - logits from LDS Ldump[32][324] via ds_read_b128 (pad 324: dump-writes and
//     transposed reads both <=2-way bank aliases; 16B-aligned)
//   - gn via float4 global loads (16 B/lane, 1/4 the requests of the old layout)
//   - reductions are 4-step 16-lane butterflies (6 shuffle-ops/task vs 36)
//   - values live in 40 statically-indexed VGPRs across both passes (no spill)
__global__ __launch_bounds__(512, 2) void fused_kernel(
    const float* __restrict__ x,       // [N_ROWS, C_DIM] fp32
    const _Float16* __restrict__ whT,  // swizzled fp16 hi of W
    const float* __restrict__ bias,    // [GV]
    const float* __restrict__ gn,      // [2*N_ROWS, V_DIM]
    const float* __restrict__ cb,      // [GV, D_DIM]
    float* __restrict__ q,             // [N_ROWS, 512]
    float* __restrict__ mf,            // [NBUCKET, GV] atomic softmax partials (pre-zeroed)
    int* __restrict__ mi) {            // [NBUCKET, GV] atomic argmax counts (pre-zeroed)
  // LDS map: GEMM: B 2x40960 | A-hi 2x4096 | A-lo 2x4096 = 98304 B
  //          epilogue: Ldump = 32 x 324 fp32 (41472 B) reuses [0, 41472)
  __shared__ __align__(16) char smemU[98304];
  _Float16* BhL = (_Float16*)smemU;
  _Float16* AhL = (_Float16*)(smemU + 81920);
  _Float16* AlL = (_Float16*)(smemU + 90112);
  float* Ldump  = (float*)smemU;
  __shared__ float accL[GV];
  __shared__ int   cntL[GV];

  const int tid = threadIdx.x;
  const int lane = tid & 63;
  const int w = tid >> 6;          // wave 0..7
  const int m0 = blockIdx.x * MROWS;
  const int frow = lane & 15;
  const int quad = lane >> 4;

  for (int e = tid; e < GV; e += 512) { accL[e] = 0.0f; cntL[e] = 0; }

  // A staging map: thread -> (row ar, 4-float k-chunk ak) of 64x32 fp32 tile
  const int ar = tid >> 3;           // 0..63
  const int ak = (tid & 7) * 4;      // 0,4,...,28
  const int ac = ak >> 3;            // chunk 0..3
  const int ah_off = ak & 7;         // 0 or 4 within 8-half chunk
  const float* xp = x + (size_t)(m0 + ar) * C_DIM + ak;

  float4v acc[4][5];
#pragma unroll
  for (int i = 0; i < 4; ++i)
#pragma unroll
    for (int j = 0; j < 5; ++j) acc[i][j] = (float4v)0.0f;

  auto stageB = [&](int kb, _Float16* Bh) {
    const _Float16* bsrc = whT + (size_t)kb * 2560 * 8;
#pragma unroll
    for (int s = 0; s < 5; ++s) {
      const int c = s * 512 + tid;   // 2560 16B chunks, lane-linear both sides
      __builtin_amdgcn_global_load_lds(GLB_AS(bsrc + (size_t)c * 8),
                                       LDS_AS(Bh + c * 8), 16, 0, 0);
    }
  };
  auto splitA = [&](const float4& a4, _Float16* Ah, _Float16* Al) {
    const _Float16 h0 = (_Float16)a4.x, h1 = (_Float16)a4.y;
    const _Float16 h2 = (_Float16)a4.z, h3 = (_Float16)a4.w;
    half4v hv, lv;
    hv[0] = h0; hv[1] = h1; hv[2] = h2; hv[3] = h3;
    lv[0] = (_Float16)(a4.x - (float)h0);
    lv[1] = (_Float16)(a4.y - (float)h1);
    lv[2] = (_Float16)(a4.z - (float)h2);
    lv[3] = (_Float16)(a4.w - (float)h3);
    *(half4v*)&Ah[(ac * 64 + ar) * 8 + ah_off] = hv;
    *(half4v*)&Al[(ac * 64 + ar) * 8 + ah_off] = lv;
  };

  // ---- prologue ----
  float4 a4 = *(const float4*)xp;
  stageB(0, BhL);
  splitA(a4, AhL, AlL);
  a4 = *(const float4*)(xp + 32);
  __syncthreads();

  // ---- main loop: 32 K-iters, single barrier each ----
  for (int kb = 0; kb < 32; ++kb) {
    const int cur = kb & 1;
    _Float16* BhC = BhL + cur * 20480;
    _Float16* AhC = AhL + cur * 2048;
    _Float16* AlC = AlL + cur * 2048;

    if (kb < 31) {
      const int nxt = cur ^ 1;
      stageB(kb + 1, BhL + nxt * 20480);
      splitA(a4, AhL + nxt * 2048, AlL + nxt * 2048);
      if (kb < 30) a4 = *(const float4*)(xp + (kb + 2) * 32);
    }

    half8 ah[4], al[4];
#pragma unroll
    for (int i = 0; i < 4; ++i) {
      ah[i] = *(const half8*)&AhC[(quad * 64 + 16 * i + frow) * 8];
      al[i] = *(const half8*)&AlC[(quad * 64 + 16 * i + frow) * 8];
    }
#pragma unroll
    for (int j = 0; j < 5; ++j) {
      const half8 bh = *(const half8*)&BhC[(quad * 640 + 80 * w + 16 * j + frow) * 8];
#pragma unroll
      for (int i = 0; i < 4; ++i) {
        acc[i][j] = __builtin_amdgcn_mfma_f32_16x16x32_f16(ah[i], bh, acc[i][j], 0, 0, 0);
        acc[i][j] = __builtin_amdgcn_mfma_f32_16x16x32_f16(al[i], bh, acc[i][j], 0, 0, 0);
      }
    }
    __syncthreads();
  }

  // bias for this wave's cols
  float bw[5];
#pragma unroll
  for (int j = 0; j < 5; ++j) bw[j] = bias[80 * w + 16 * j + frow];

  // -------- epilogue: 4 phases = 2 groups x 2 row-halves --------
  const int rl = tid >> 4;     // 0..31: row within phase
  const int h  = tid & 15;     // 16-lane slot within row

#pragma unroll 1
  for (int g = 0; g < G_DIM; ++g) {
#pragma unroll 1
    for (int hh = 0; hh < 2; ++hh) {
      __syncthreads();  // previous phase's Ldump reads (or GEMM LDS use) done
      if ((w >> 2) == g) {
        const int cg0 = 80 * (w & 3) + frow;
#pragma unroll
        for (int ii = 0; ii < 2; ++ii) {
          const int i = 2 * hh + ii;
#pragma unroll
          for (int j = 0; j < 5; ++j)
#pragma unroll
            for (int r = 0; r < 4; ++r)
              Ldump[(16 * ii + 4 * quad + r) * 324 + cg0 + 16 * j] = acc[i][j][r] + bw[j];
        }
      }
      __syncthreads();

      const int n = m0 + hh * 32 + rl;
      const float* gp = gn + (size_t)(2 * n + g) * V_DIM + 20 * h;
      const float* lp = Ldump + rl * 324 + 20 * h;

      // ---- pass 1: load 20 l (LDS b128) + 20 gn (global f4); running argmax ----
      float4v L[5], T[5];
      float m = -3.0e38f, tm = -3.0e38f;
      int midx = 0, tidx = 0;
#pragma unroll
      for (int cc = 0; cc < 5; ++cc) {
        const float4v lv = *(const float4v*)(lp + 4 * cc);
        const float4v gv = *(const float4v*)(gp + 4 * cc);
        float4v tv;
#pragma unroll
        for (int e2 = 0; e2 < 4; ++e2) tv[e2] = (lv[e2] + gv[e2]) * 0.5f;
        L[cc] = lv; T[cc] = tv;
#pragma unroll
        for (int e2 = 0; e2 < 4; ++e2) {
          const int v = 20 * h + 4 * cc + e2;
          if (lv[e2] > m)  { m = lv[e2];  midx = v; }   // ascending scan: > keeps first
          if (tv[e2] > tm) { tm = tv[e2]; tidx = v; }
        }
      }
      // 16-lane butterfly argmax (first-index on ties)
#pragma unroll
      for (int off = 8; off > 0; off >>= 1) {
        const float om = __shfl_xor(m, off, 64);
        const int   oi = __shfl_xor(midx, off, 64);
        if (om > m || (om == m && oi < midx)) { m = om; midx = oi; }
        const float ot  = __shfl_xor(tm, off, 64);
        const int   oti = __shfl_xor(tidx, off, 64);
        if (ot > tm || (ot == tm && oti < tidx)) { tm = ot; tidx = oti; }
      }

      // ---- pass 2: exp sums (values already in registers) ----
      float sl = 0.0f, st = 0.0f;
#pragma unroll
      for (int cc = 0; cc < 5; ++cc)
#pragma unroll
        for (int e2 = 0; e2 < 4; ++e2) {
          const float el = expf(L[cc][e2] - m);
          L[cc][e2] = el;               // keep e^l for prob accumulation
          sl += el;
          st += expf(T[cc][e2] - tm);
        }
#pragma unroll
      for (int off = 8; off > 0; off >>= 1) {
        sl += __shfl_xor(sl, off, 64);
        st += __shfl_xor(st, off, 64);
      }
      const float inv = 1.0f / sl;
      const float sv = 1.0f / st;
      const float yv = (1.0f + sv) - sv;  // straight-through value at argmax

      // prob-softmax accumulation (per-value, per-lane addresses)
#pragma unroll
      for (int cc = 0; cc < 5; ++cc)
#pragma unroll
        for (int e2 = 0; e2 < 4; ++e2)
          atomicAdd(&accL[g * V_DIM + 20 * h + 4 * cc + e2], L[cc][e2] * inv);
      if (h == 0) atomicAdd(&cntL[g * V_DIM + midx], 1);

      // q output: 16 lanes x 4 float4 = the 256-wide codebook row, scaled by yv
      const float4v* cbp = (const float4v*)cb + (size_t)(g * V_DIM + tidx) * 64;
      float4v* qp = (float4v*)q + (size_t)n * 128 + g * 64;
#pragma unroll
      for (int k2 = 0; k2 < 4; ++k2) {
        const float4v c4 = cbp[h + 16 * k2];
        float4v o4;
#pragma unroll
        for (int e2 = 0; e2 < 4; ++e2) o4[e2] = yv * c4[e2];
        qp[h + 16 * k2] = o4;
      }
    }
  }

  __syncthreads();
  const size_t pb = (size_t)(blockIdx.x & (NBUCKET - 1)) * GV;
  for (int e = tid; e < GV; e += 512) {
    atomicAdd(&mf[pb + e], accL[e]);
    atomicAdd(&mi[pb + e], cntL[e]);
  }
}

// ---------------- Finalize: sum 64 buckets, entropies, outputs ----------------
__global__ __launch_bounds__(640) void finalize_kernel(
    const float* __restrict__ mf, const int* __restrict__ mi,
    float* __restrict__ out3) {
  __shared__ float sA[G_DIM];
  __shared__ float sC[G_DIM];
  const int t = threadIdx.x;        // 0..639 == e
  if (t < G_DIM) { sA[t] = 0.0f; sC[t] = 0.0f; }
  __syncthreads();

  const int g = t / V_DIM;          // wave-uniform
  float f = 0.0f;
  int   c = 0;
#pragma unroll 8
  for (int b = 0; b < NBUCKET; ++b) {
    f += mf[(size_t)b * GV + t];
    c += mi[(size_t)b * GV + t];
  }
  const float pa = f * (1.0f / 16384.0f);
  const float ph = (float)c * (1.0f / 16384.0f);
  float a = pa * logf(pa + 1e-7f);
  float h = ph * logf(ph + 1e-7f);
#pragma unroll
  for (int off = 32; off > 0; off >>= 1) {
    a += __shfl_xor(a, off, 64);
    h += __shfl_xor(h, off, 64);
  }
  if ((t & 63) == 0) {
    atomicAdd(&sA[g], a);
    atomicAdd(&sC[g], h);
  }
  __syncthreads();
  if (t == 0) {
    const float code_p = expf(-sC[0]) + expf(-sC[1]);
    const float prob_p = expf(-sA[0]) + expf(-sA[1]);
    out3[0] = code_p;
    out3[1] = prob_p;
    out3[2] = ((float)GV - prob_p) / (float)GV;
  }
}

extern "C" void kernel_launch(void* const* d_in, const int* in_sizes, int n_in,
                              void* d_out, int out_size, void* d_ws, size_t ws_size,
                              hipStream_t stream) {
  const float* x  = (const float*)d_in[0];  // [8,2048,1024]
  const float* W  = (const float*)d_in[1];  // [640,1024]
  const float* b  = (const float*)d_in[2];  // [640]
  const float* cb = (const float*)d_in[3];  // [1,640,256]
  const float* gn = (const float*)d_in[4];  // [32768,320]
  float* out = (float*)d_out;               // q [16384*512] + 3 scalars

  char* ws = (char*)d_ws;
  _Float16* whT = (_Float16*)ws;             // 1,310,720 B
  float* mf = (float*)(ws + 1310720);        // 64*640*4 = 163,840 B
  int*   mi = (int*)  (ws + 1474560);        // 163,840 B

  // wsplit also zeroes mf+mi (327,680 B = 81,920 threads x 4 B)
  wsplit_kernel<<<(GV * C_DIM / 8) / 256, 256, 0, stream>>>(W, whT, (int*)mf);

  fused_kernel<<<FBLKS, 512, 0, stream>>>(x, whT, b, gn, cb, out, mf, mi);

  finalize_kernel<<<1, 640, 0, stream>>>(mf, mi, out + (size_t)N_ROWS * 512);
}

// Round 5
// 233.894 us; speedup vs baseline: 1.9662x; 1.9662x over previous
//
#include <hip/hip_runtime.h>

// Problem constants
#define N_ROWS 16384   // B*T
#define C_DIM  1024
#define GV     640     // G*V
#define V_DIM  320
#define G_DIM  2
#define D_DIM  256
#define MROWS  64      // rows per fused block
#define FBLKS  (N_ROWS / MROWS)  // 256 = exactly 1 block/CU
#define NBUCKET 64

typedef __attribute__((ext_vector_type(8))) _Float16 half8;
typedef __attribute__((ext_vector_type(4))) _Float16 half4v;
typedef __attribute__((ext_vector_type(4))) float float4v;

#define LDS_AS(p) ((__attribute__((address_space(3))) unsigned int*)(p))
#define GLB_AS(p) ((const __attribute__((address_space(1))) unsigned int*)(p))

// ---------------- W -> fp16 hi, pre-swizzled into 16B-chunk-transposed layout ----
// whT[((kb*4 + c)*640 + n)*8 + h] = (half)W[n][kb*32 + c*8 + h]
// Also zeroes the mf/mi atomic-partial region (81,920 threads x 4 B = 327,680 B).
__global__ __launch_bounds__(256) void wsplit_kernel(const float* __restrict__ src,
                                                     _Float16* __restrict__ dst,
                                                     int* __restrict__ zr) {
  const int t = blockIdx.x * 256 + threadIdx.x;  // 0..81919
  zr[t] = 0;
  const int n = t % GV;
  const int cc = t / GV;       // 0..127 ; k = cc*8
  const int k = cc * 8;
  const float4 v0 = *(const float4*)(src + (size_t)n * C_DIM + k);
  const float4 v1 = *(const float4*)(src + (size_t)n * C_DIM + k + 4);
  half8 h;
  h[0] = (_Float16)v0.x; h[1] = (_Float16)v0.y; h[2] = (_Float16)v0.z; h[3] = (_Float16)v0.w;
  h[4] = (_Float16)v1.x; h[5] = (_Float16)v1.y; h[6] = (_Float16)v1.z; h[7] = (_Float16)v1.w;
  *(half8*)(dst + (size_t)t * 8) = h;
}

// ---------------- Fused: GEMM (M=64 x N=640 per block) + transposed epilogue ----
// GEMM loop identical to the round-1/2 version (double-buffered, 1 barrier/iter).
// Epilogue: 4 FULLY-UNROLLED phases (2 groups x 2 row-halves of 32 rows).
// CRITICAL (rule #20): the phase loops MUST be fully unrolled — acc[2*hh+ii]
// with runtime hh demotes acc[4][5] to scratch, and every MFMA in the main
// loop then round-trips through memory (round-4: 1.38 GB WRITE_SIZE, 3.5x).
// Per phase, each row is handled by 16 lanes scanning 20 values each:
//   - logits from LDS Ldump[32][324] via ds_read_b128 (pad 324)
//   - gn via float4 global loads (16 B/lane)
//   - reductions are 4-step 16-lane butterflies
__global__ __launch_bounds__(512, 2) void fused_kernel(
    const float* __restrict__ x,       // [N_ROWS, C_DIM] fp32
    const _Float16* __restrict__ whT,  // swizzled fp16 hi of W
    const float* __restrict__ bias,    // [GV]
    const float* __restrict__ gn,      // [2*N_ROWS, V_DIM]
    const float* __restrict__ cb,      // [GV, D_DIM]
    float* __restrict__ q,             // [N_ROWS, 512]
    float* __restrict__ mf,            // [NBUCKET, GV] atomic softmax partials (pre-zeroed)
    int* __restrict__ mi) {            // [NBUCKET, GV] atomic argmax counts (pre-zeroed)
  // LDS map: GEMM: B 2x40960 | A-hi 2x4096 | A-lo 2x4096 = 98304 B
  //          epilogue: Ldump = 32 x 324 fp32 (41472 B) reuses [0, 41472)
  __shared__ __align__(16) char smemU[98304];
  _Float16* BhL = (_Float16*)smemU;
  _Float16* AhL = (_Float16*)(smemU + 81920);
  _Float16* AlL = (_Float16*)(smemU + 90112);
  float* Ldump  = (float*)smemU;
  __shared__ float accL[GV];
  __shared__ int   cntL[GV];

  const int tid = threadIdx.x;
  const int lane = tid & 63;
  const int w = tid >> 6;          // wave 0..7
  const int m0 = blockIdx.x * MROWS;
  const int frow = lane & 15;
  const int quad = lane >> 4;

  for (int e = tid; e < GV; e += 512) { accL[e] = 0.0f; cntL[e] = 0; }

  // A staging map: thread -> (row ar, 4-float k-chunk ak) of 64x32 fp32 tile
  const int ar = tid >> 3;           // 0..63
  const int ak = (tid & 7) * 4;      // 0,4,...,28
  const int ac = ak >> 3;            // chunk 0..3
  const int ah_off = ak & 7;         // 0 or 4 within 8-half chunk
  const float* xp = x + (size_t)(m0 + ar) * C_DIM + ak;

  float4v acc[4][5];
#pragma unroll
  for (int i = 0; i < 4; ++i)
#pragma unroll
    for (int j = 0; j < 5; ++j) acc[i][j] = (float4v)0.0f;

  auto stageB = [&](int kb, _Float16* Bh) {
    const _Float16* bsrc = whT + (size_t)kb * 2560 * 8;
#pragma unroll
    for (int s = 0; s < 5; ++s) {
      const int c = s * 512 + tid;   // 2560 16B chunks, lane-linear both sides
      __builtin_amdgcn_global_load_lds(GLB_AS(bsrc + (size_t)c * 8),
                                       LDS_AS(Bh + c * 8), 16, 0, 0);
    }
  };
  auto splitA = [&](const float4& a4, _Float16* Ah, _Float16* Al) {
    const _Float16 h0 = (_Float16)a4.x, h1 = (_Float16)a4.y;
    const _Float16 h2 = (_Float16)a4.z, h3 = (_Float16)a4.w;
    half4v hv, lv;
    hv[0] = h0; hv[1] = h1; hv[2] = h2; hv[3] = h3;
    lv[0] = (_Float16)(a4.x - (float)h0);
    lv[1] = (_Float16)(a4.y - (float)h1);
    lv[2] = (_Float16)(a4.z - (float)h2);
    lv[3] = (_Float16)(a4.w - (float)h3);
    *(half4v*)&Ah[(ac * 64 + ar) * 8 + ah_off] = hv;
    *(half4v*)&Al[(ac * 64 + ar) * 8 + ah_off] = lv;
  };

  // ---- prologue ----
  float4 a4 = *(const float4*)xp;
  stageB(0, BhL);
  splitA(a4, AhL, AlL);
  a4 = *(const float4*)(xp + 32);
  __syncthreads();

  // ---- main loop: 32 K-iters, single barrier each ----
  for (int kb = 0; kb < 32; ++kb) {
    const int cur = kb & 1;
    _Float16* BhC = BhL + cur * 20480;
    _Float16* AhC = AhL + cur * 2048;
    _Float16* AlC = AlL + cur * 2048;

    if (kb < 31) {
      const int nxt = cur ^ 1;
      stageB(kb + 1, BhL + nxt * 20480);
      splitA(a4, AhL + nxt * 2048, AlL + nxt * 2048);
      if (kb < 30) a4 = *(const float4*)(xp + (kb + 2) * 32);
    }

    half8 ah[4], al[4];
#pragma unroll
    for (int i = 0; i < 4; ++i) {
      ah[i] = *(const half8*)&AhC[(quad * 64 + 16 * i + frow) * 8];
      al[i] = *(const half8*)&AlC[(quad * 64 + 16 * i + frow) * 8];
    }
#pragma unroll
    for (int j = 0; j < 5; ++j) {
      const half8 bh = *(const half8*)&BhC[(quad * 640 + 80 * w + 16 * j + frow) * 8];
#pragma unroll
      for (int i = 0; i < 4; ++i) {
        acc[i][j] = __builtin_amdgcn_mfma_f32_16x16x32_f16(ah[i], bh, acc[i][j], 0, 0, 0);
        acc[i][j] = __builtin_amdgcn_mfma_f32_16x16x32_f16(al[i], bh, acc[i][j], 0, 0, 0);
      }
    }
    __syncthreads();
  }

  // bias for this wave's cols
  float bw[5];
#pragma unroll
  for (int j = 0; j < 5; ++j) bw[j] = bias[80 * w + 16 * j + frow];

  // -------- epilogue: 4 phases = 2 groups x 2 row-halves, FULLY UNROLLED --------
  const int rl = tid >> 4;     // 0..31: row within phase
  const int h  = tid & 15;     // 16-lane slot within row

#pragma unroll
  for (int g = 0; g < G_DIM; ++g) {
#pragma unroll
    for (int hh = 0; hh < 2; ++hh) {
      __syncthreads();  // previous phase's Ldump reads (or GEMM LDS use) done
      if ((w >> 2) == g) {
        const int cg0 = 80 * (w & 3) + frow;
#pragma unroll
        for (int ii = 0; ii < 2; ++ii) {
          const int i = 2 * hh + ii;   // compile-time constant (all loops unrolled)
#pragma unroll
          for (int j = 0; j < 5; ++j)
#pragma unroll
            for (int r = 0; r < 4; ++r)
              Ldump[(16 * ii + 4 * quad + r) * 324 + cg0 + 16 * j] = acc[i][j][r] + bw[j];
        }
      }
      __syncthreads();

      const int n = m0 + hh * 32 + rl;
      const float* gp = gn + (size_t)(2 * n + g) * V_DIM + 20 * h;
      const float* lp = Ldump + rl * 324 + 20 * h;

      // ---- pass 1: load 20 l (LDS b128) + 20 gn (global f4); running argmax ----
      float4v L[5], T[5];
      float m = -3.0e38f, tm = -3.0e38f;
      int midx = 0, tidx = 0;
#pragma unroll
      for (int cc = 0; cc < 5; ++cc) {
        const float4v lv = *(const float4v*)(lp + 4 * cc);
        const float4v gv = *(const float4v*)(gp + 4 * cc);
        float4v tv;
#pragma unroll
        for (int e2 = 0; e2 < 4; ++e2) tv[e2] = (lv[e2] + gv[e2]) * 0.5f;
        L[cc] = lv; T[cc] = tv;
#pragma unroll
        for (int e2 = 0; e2 < 4; ++e2) {
          const int v = 20 * h + 4 * cc + e2;
          if (lv[e2] > m)  { m = lv[e2];  midx = v; }   // ascending scan: > keeps first
          if (tv[e2] > tm) { tm = tv[e2]; tidx = v; }
        }
      }
      // 16-lane butterfly argmax (first-index on ties)
#pragma unroll
      for (int off = 8; off > 0; off >>= 1) {
        const float om = __shfl_xor(m, off, 64);
        const int   oi = __shfl_xor(midx, off, 64);
        if (om > m || (om == m && oi < midx)) { m = om; midx = oi; }
        const float ot  = __shfl_xor(tm, off, 64);
        const int   oti = __shfl_xor(tidx, off, 64);
        if (ot > tm || (ot == tm && oti < tidx)) { tm = ot; tidx = oti; }
      }

      // ---- pass 2: exp sums (values already in registers) ----
      float sl = 0.0f, st = 0.0f;
#pragma unroll
      for (int cc = 0; cc < 5; ++cc)
#pragma unroll
        for (int e2 = 0; e2 < 4; ++e2) {
          const float el = expf(L[cc][e2] - m);
          L[cc][e2] = el;               // keep e^l for prob accumulation
          sl += el;
          st += expf(T[cc][e2] - tm);
        }
#pragma unroll
      for (int off = 8; off > 0; off >>= 1) {
        sl += __shfl_xor(sl, off, 64);
        st += __shfl_xor(st, off, 64);
      }
      const float inv = 1.0f / sl;
      const float sv = 1.0f / st;
      const float yv = (1.0f + sv) - sv;  // straight-through value at argmax

      // prob-softmax accumulation (per-value, per-lane addresses)
#pragma unroll
      for (int cc = 0; cc < 5; ++cc)
#pragma unroll
        for (int e2 = 0; e2 < 4; ++e2)
          atomicAdd(&accL[g * V_DIM + 20 * h + 4 * cc + e2], L[cc][e2] * inv);
      if (h == 0) atomicAdd(&cntL[g * V_DIM + midx], 1);

      // q output: 16 lanes x 4 float4 = the 256-wide codebook row, scaled by yv
      const float4v* cbp = (const float4v*)cb + (size_t)(g * V_DIM + tidx) * 64;
      float4v* qp = (float4v*)q + (size_t)n * 128 + g * 64;
#pragma unroll
      for (int k2 = 0; k2 < 4; ++k2) {
        const float4v c4 = cbp[h + 16 * k2];
        float4v o4;
#pragma unroll
        for (int e2 = 0; e2 < 4; ++e2) o4[e2] = yv * c4[e2];
        qp[h + 16 * k2] = o4;
      }
    }
  }

  __syncthreads();
  const size_t pb = (size_t)(blockIdx.x & (NBUCKET - 1)) * GV;
  for (int e = tid; e < GV; e += 512) {
    atomicAdd(&mf[pb + e], accL[e]);
    atomicAdd(&mi[pb + e], cntL[e]);
  }
}

// ---------------- Finalize: sum 64 buckets, entropies, outputs ----------------
__global__ __launch_bounds__(640) void finalize_kernel(
    const float* __restrict__ mf, const int* __restrict__ mi,
    float* __restrict__ out3) {
  __shared__ float sA[G_DIM];
  __shared__ float sC[G_DIM];
  const int t = threadIdx.x;        // 0..639 == e
  if (t < G_DIM) { sA[t] = 0.0f; sC[t] = 0.0f; }
  __syncthreads();

  const int g = t / V_DIM;          // wave-uniform
  float f = 0.0f;
  int   c = 0;
#pragma unroll 8
  for (int b = 0; b < NBUCKET; ++b) {
    f += mf[(size_t)b * GV + t];
    c += mi[(size_t)b * GV + t];
  }
  const float pa = f * (1.0f / 16384.0f);
  const float ph = (float)c * (1.0f / 16384.0f);
  float a = pa * logf(pa + 1e-7f);
  float h = ph * logf(ph + 1e-7f);
#pragma unroll
  for (int off = 32; off > 0; off >>= 1) {
    a += __shfl_xor(a, off, 64);
    h += __shfl_xor(h, off, 64);
  }
  if ((t & 63) == 0) {
    atomicAdd(&sA[g], a);
    atomicAdd(&sC[g], h);
  }
  __syncthreads();
  if (t == 0) {
    const float code_p = expf(-sC[0]) + expf(-sC[1]);
    const float prob_p = expf(-sA[0]) + expf(-sA[1]);
    out3[0] = code_p;
    out3[1] = prob_p;
    out3[2] = ((float)GV - prob_p) / (float)GV;
  }
}

extern "C" void kernel_launch(void* const* d_in, const int* in_sizes, int n_in,
                              void* d_out, int out_size, void* d_ws, size_t ws_size,
                              hipStream_t stream) {
  const float* x  = (const float*)d_in[0];  // [8,2048,1024]
  const float* W  = (const float*)d_in[1];  // [640,1024]
  const float* b  = (const float*)d_in[2];  // [640]
  const float* cb = (const float*)d_in[3];  // [1,640,256]
  const float* gn = (const float*)d_in[4];  // [32768,320]
  float* out = (float*)d_out;               // q [16384*512] + 3 scalars

  char* ws = (char*)d_ws;
  _Float16* whT = (_Float16*)ws;             // 1,310,720 B
  float* mf = (float*)(ws + 1310720);        // 64*640*4 = 163,840 B
  int*   mi = (int*)  (ws + 1474560);        // 163,840 B

  // wsplit also zeroes mf+mi (327,680 B = 81,920 threads x 4 B)
  wsplit_kernel<<<(GV * C_DIM / 8) / 256, 256, 0, stream>>>(W, whT, (int*)mf);

  fused_kernel<<<FBLKS, 512, 0, stream>>>(x, whT, b, gn, cb, out, mf, mi);

  finalize_kernel<<<1, 640, 0, stream>>>(mf, mi, out + (size_t)N_ROWS * 512);
}

// Round 6
// 203.083 us; speedup vs baseline: 2.2645x; 1.1517x over previous
//
#include <hip/hip_runtime.h>

// Problem constants
#define N_ROWS 16384   // B*T
#define C_DIM  1024
#define GV     640     // G*V
#define V_DIM  320
#define G_DIM  2
#define D_DIM  256
#define MROWS  64      // rows per fused block
#define FBLKS  (N_ROWS / MROWS)  // 256 = exactly 1 block/CU
#define NBUCKET 64

typedef __attribute__((ext_vector_type(8))) _Float16 half8;
typedef __attribute__((ext_vector_type(4))) _Float16 half4v;
typedef __attribute__((ext_vector_type(4))) float float4v;

#define LDS_AS(p) ((__attribute__((address_space(3))) unsigned int*)(p))
#define GLB_AS(p) ((const __attribute__((address_space(1))) unsigned int*)(p))

// ---------------- W -> fp16 hi, pre-swizzled into 16B-chunk-transposed layout ----
// whT[((kb*4 + c)*640 + n)*8 + h] = (half)W[n][kb*32 + c*8 + h]
// Also zeroes the mf/mi atomic-partial region (81,920 threads x 4 B = 327,680 B).
__global__ __launch_bounds__(256) void wsplit_kernel(const float* __restrict__ src,
                                                     _Float16* __restrict__ dst,
                                                     int* __restrict__ zr) {
  const int t = blockIdx.x * 256 + threadIdx.x;  // 0..81919
  zr[t] = 0;
  const int n = t % GV;
  const int cc = t / GV;       // 0..127 ; k = cc*8
  const int k = cc * 8;
  const float4 v0 = *(const float4*)(src + (size_t)n * C_DIM + k);
  const float4 v1 = *(const float4*)(src + (size_t)n * C_DIM + k + 4);
  half8 h;
  h[0] = (_Float16)v0.x; h[1] = (_Float16)v0.y; h[2] = (_Float16)v0.z; h[3] = (_Float16)v0.w;
  h[4] = (_Float16)v1.x; h[5] = (_Float16)v1.y; h[6] = (_Float16)v1.z; h[7] = (_Float16)v1.w;
  *(half8*)(dst + (size_t)t * 8) = h;
}

// ---------------- Fused: GEMM (M=64 x N=640 per block) + in-acc epilogue ----------
// GEMM loop identical to round-2 (double-buffered, 1 barrier/iter).
// Epilogue operates directly on the MFMA accumulator layout (NO Ldump round-trip):
//   wave w owns cols [80w, 80w+80); g = w>>2; both groups run CONCURRENTLY.
//   thread (w,quad,frow) holds rows 16i+4quad+r (i,r in 0..3), cols 80(w&3)+16j+frow.
// Phase A: per row: l = acc+bias; gn loaded coalesced; in-lane(5) + 16-lane
//   butterfly max/argmax; ONLINE partial sums sl = sum exp(l - ml_wave) (e' kept
//   in acc regs), st likewise; 8-dword partial per (row,wave) -> combW LDS.
// Phase A2: 128 threads combine 4 wave partials/row (rescale by exp(ml_w - m)),
//   cnt atomic, write back {m, 1/sl, yv, tidx} per row.
// Phase CD: accL += e' * exp(ml_w - m) * inv (5 atomics/thread, 4-way contention);
//   q written coalesced, one wave-task per row-group.
__global__ __launch_bounds__(512, 2) void fused_kernel(
    const float* __restrict__ x,       // [N_ROWS, C_DIM] fp32
    const _Float16* __restrict__ whT,  // swizzled fp16 hi of W
    const float* __restrict__ bias,    // [GV]
    const float* __restrict__ gn,      // [2*N_ROWS, V_DIM]
    const float* __restrict__ cb,      // [GV, D_DIM]
    float* __restrict__ q,             // [N_ROWS, 512]
    float* __restrict__ mf,            // [NBUCKET, GV] atomic softmax partials (pre-zeroed)
    int* __restrict__ mi) {            // [NBUCKET, GV] atomic argmax counts (pre-zeroed)
  // LDS map: GEMM: B 2x40960 | A-hi 2x4096 | A-lo 2x4096 = 98304 B
  //   epilogue reuse: combW[128 rows][36 dwords] = 18,432 B  (8-dword partials x4 waves, pad 36)
  //                   wbL  [128 rows][4 dwords] =  2,048 B  at +18432
  __shared__ __align__(16) char smemU[98304];
  _Float16* BhL = (_Float16*)smemU;
  _Float16* AhL = (_Float16*)(smemU + 81920);
  _Float16* AlL = (_Float16*)(smemU + 90112);
  float* combW  = (float*)smemU;
  float* wbL    = (float*)(smemU + 18432);
  __shared__ float accL[GV];
  __shared__ int   cntL[GV];

  const int tid = threadIdx.x;
  const int lane = tid & 63;
  const int w = tid >> 6;          // wave 0..7
  const int m0 = blockIdx.x * MROWS;
  const int frow = lane & 15;
  const int quad = lane >> 4;

  for (int e = tid; e < GV; e += 512) { accL[e] = 0.0f; cntL[e] = 0; }

  // A staging map: thread -> (row ar, 4-float k-chunk ak) of 64x32 fp32 tile
  const int ar = tid >> 3;           // 0..63
  const int ak = (tid & 7) * 4;      // 0,4,...,28
  const int ac = ak >> 3;            // chunk 0..3
  const int ah_off = ak & 7;         // 0 or 4 within 8-half chunk
  const float* xp = x + (size_t)(m0 + ar) * C_DIM + ak;

  float4v acc[4][5];
#pragma unroll
  for (int i = 0; i < 4; ++i)
#pragma unroll
    for (int j = 0; j < 5; ++j) acc[i][j] = (float4v)0.0f;

  auto stageB = [&](int kb, _Float16* Bh) {
    const _Float16* bsrc = whT + (size_t)kb * 2560 * 8;
#pragma unroll
    for (int s = 0; s < 5; ++s) {
      const int c = s * 512 + tid;   // 2560 16B chunks, lane-linear both sides
      __builtin_amdgcn_global_load_lds(GLB_AS(bsrc + (size_t)c * 8),
                                       LDS_AS(Bh + c * 8), 16, 0, 0);
    }
  };
  auto splitA = [&](const float4& a4, _Float16* Ah, _Float16* Al) {
    const _Float16 h0 = (_Float16)a4.x, h1 = (_Float16)a4.y;
    const _Float16 h2 = (_Float16)a4.z, h3 = (_Float16)a4.w;
    half4v hv, lv;
    hv[0] = h0; hv[1] = h1; hv[2] = h2; hv[3] = h3;
    lv[0] = (_Float16)(a4.x - (float)h0);
    lv[1] = (_Float16)(a4.y - (float)h1);
    lv[2] = (_Float16)(a4.z - (float)h2);
    lv[3] = (_Float16)(a4.w - (float)h3);
    *(half4v*)&Ah[(ac * 64 + ar) * 8 + ah_off] = hv;
    *(half4v*)&Al[(ac * 64 + ar) * 8 + ah_off] = lv;
  };

  // ---- prologue ----
  float4 a4 = *(const float4*)xp;
  stageB(0, BhL);
  splitA(a4, AhL, AlL);
  a4 = *(const float4*)(xp + 32);
  __syncthreads();

  // ---- main loop: 32 K-iters, single barrier each ----
  for (int kb = 0; kb < 32; ++kb) {
    const int cur = kb & 1;
    _Float16* BhC = BhL + cur * 20480;
    _Float16* AhC = AhL + cur * 2048;
    _Float16* AlC = AlL + cur * 2048;

    if (kb < 31) {
      const int nxt = cur ^ 1;
      stageB(kb + 1, BhL + nxt * 20480);
      splitA(a4, AhL + nxt * 2048, AlL + nxt * 2048);
      if (kb < 30) a4 = *(const float4*)(xp + (kb + 2) * 32);
    }

    half8 ah[4], al[4];
#pragma unroll
    for (int i = 0; i < 4; ++i) {
      ah[i] = *(const half8*)&AhC[(quad * 64 + 16 * i + frow) * 8];
      al[i] = *(const half8*)&AlC[(quad * 64 + 16 * i + frow) * 8];
    }
#pragma unroll
    for (int j = 0; j < 5; ++j) {
      const half8 bh = *(const half8*)&BhC[(quad * 640 + 80 * w + 16 * j + frow) * 8];
#pragma unroll
      for (int i = 0; i < 4; ++i) {
        acc[i][j] = __builtin_amdgcn_mfma_f32_16x16x32_f16(ah[i], bh, acc[i][j], 0, 0, 0);
        acc[i][j] = __builtin_amdgcn_mfma_f32_16x16x32_f16(al[i], bh, acc[i][j], 0, 0, 0);
      }
    }
    __syncthreads();  // last iter: GEMM LDS dead after this -> combW reuse safe
  }

  // bias for this wave's cols
  float bw[5];
#pragma unroll
  for (int j = 0; j < 5; ++j) bw[j] = bias[80 * w + 16 * j + frow];

  const int g  = w >> 2;   // group handled by this wave
  const int wq = w & 3;    // col-slice within group: cols 80*wq + 16j + frow

  // -------- Phase A: per-row wave-slice reductions (16 rows, fully unrolled) -----
  float mlk[4][4];   // per-row wave-slice l-max (basis of stored e')
#pragma unroll
  for (int i = 0; i < 4; ++i) {
#pragma unroll
    for (int r = 0; r < 4; ++r) {
      const int row = 16 * i + 4 * quad + r;
      const int n = m0 + row;
      const float* gp = gn + (size_t)(2 * n + g) * V_DIM + 80 * wq + frow;

      float l5[5], t5[5];
#pragma unroll
      for (int j = 0; j < 5; ++j) {
        l5[j] = acc[i][j][r] + bw[j];
        t5[j] = (l5[j] + gp[16 * j]) * 0.5f;
      }
      // in-lane max + argmax (ascending j: strict > keeps first index)
      float ml = l5[0]; int il = 80 * wq + frow;
      float mt = t5[0]; int it = il;
#pragma unroll
      for (int j = 1; j < 5; ++j) {
        const int cj = 80 * wq + 16 * j + frow;
        if (l5[j] > ml) { ml = l5[j]; il = cj; }
        if (t5[j] > mt) { mt = t5[j]; it = cj; }
      }
      // 16-lane butterfly (stays within quad-group for off<16)
#pragma unroll
      for (int off = 1; off < 16; off <<= 1) {
        const float o1 = __shfl_xor(ml, off, 64); const int i1 = __shfl_xor(il, off, 64);
        if (o1 > ml || (o1 == ml && i1 < il)) { ml = o1; il = i1; }
        const float o2 = __shfl_xor(mt, off, 64); const int i2 = __shfl_xor(it, off, 64);
        if (o2 > mt || (o2 == mt && i2 < it)) { mt = o2; it = i2; }
      }
      mlk[i][r] = ml;
      // online partial sums vs wave-slice max; keep e' in acc regs
      float sl = 0.0f, st = 0.0f;
#pragma unroll
      for (int j = 0; j < 5; ++j) {
        const float el = expf(l5[j] - ml);
        acc[i][j][r] = el;
        sl += el;
        st += expf(t5[j] - mt);
      }
#pragma unroll
      for (int off = 1; off < 16; off <<= 1) {
        sl += __shfl_xor(sl, off, 64);
        st += __shfl_xor(st, off, 64);
      }
      // one writer lane per (i,r): 2 x b128 partials
      if (frow == 4 * i + r) {
        float* dst = combW + (size_t)(g * 64 + row) * 36 + wq * 8;
        float4v p1, p2;
        p1[0] = ml; p1[1] = __int_as_float(il); p1[2] = sl; p1[3] = 0.0f;
        p2[0] = mt; p2[1] = __int_as_float(it); p2[2] = st; p2[3] = 0.0f;
        *(float4v*)dst = p1;
        *(float4v*)(dst + 4) = p2;
      }
    }
  }
  __syncthreads();

  // -------- Phase A2: combine 4 wave partials per row (128 rows, 128 threads) ----
  if (tid < 128) {
    const int rg = tid;                // g*64 + row
    const float* cw = combW + (size_t)rg * 36;
    float mw[4], sw[4], tw[4], s2[4];
    int   iw[4], ti4[4];
#pragma unroll
    for (int v = 0; v < 4; ++v) {
      const float4v p1 = *(const float4v*)(cw + v * 8);
      const float4v p2 = *(const float4v*)(cw + v * 8 + 4);
      mw[v] = p1[0]; iw[v] = __float_as_int(p1[1]); sw[v] = p1[2];
      tw[v] = p2[0]; ti4[v] = __float_as_int(p2[1]); s2[v] = p2[2];
    }
    float m = mw[0]; int idx = iw[0];
    float tm = tw[0]; int ti = ti4[0];
#pragma unroll
    for (int v = 1; v < 4; ++v) {
      if (mw[v] > m || (mw[v] == m && iw[v] < idx)) { m = mw[v]; idx = iw[v]; }
      if (tw[v] > tm || (tw[v] == tm && ti4[v] < ti)) { tm = tw[v]; ti = ti4[v]; }
    }
    float sl = 0.0f, st = 0.0f;
#pragma unroll
    for (int v = 0; v < 4; ++v) {
      sl += sw[v] * expf(mw[v] - m);
      st += s2[v] * expf(tw[v] - tm);
    }
    const float inv = 1.0f / sl;
    const float sv = 1.0f / st;
    const float yv = (1.0f + sv) - sv;   // straight-through value at argmax
    const int g2 = rg >> 6;
    atomicAdd(&cntL[g2 * V_DIM + idx], 1);
    float4v wbv;
    wbv[0] = m; wbv[1] = inv; wbv[2] = yv; wbv[3] = __int_as_float(ti);
    *(float4v*)(wbL + (size_t)rg * 4) = wbv;
  }
  __syncthreads();

  // -------- Phase CD: accL accumulation + q writes --------
  float p5[5] = {0.0f, 0.0f, 0.0f, 0.0f, 0.0f};
#pragma unroll
  for (int i = 0; i < 4; ++i)
#pragma unroll
    for (int r = 0; r < 4; ++r) {
      const int row = 16 * i + 4 * quad + r;
      const float4v wbv = *(const float4v*)(wbL + (size_t)(g * 64 + row) * 4);
      const float k = expf(mlk[i][r] - wbv[0]) * wbv[1];
#pragma unroll
      for (int j = 0; j < 5; ++j) p5[j] += acc[i][j][r] * k;
    }
#pragma unroll
  for (int j = 0; j < 5; ++j)
    atomicAdd(&accL[g * V_DIM + 80 * wq + 16 * j + frow], p5[j]);  // 4-way contention

  // q: 128 tasks x 64 float4; one wave per task per iteration, fully coalesced
#pragma unroll
  for (int it2 = 0; it2 < 16; ++it2) {
    const int task = w + 8 * it2;          // 0..127 = g*64 + row
    const int tg = task >> 6, trow = task & 63;
    const float4v wbv = *(const float4v*)(wbL + (size_t)task * 4);  // broadcast
    const float yv = wbv[2];
    const int ti = __float_as_int(wbv[3]);
    const float4v c4 = ((const float4v*)cb)[(size_t)(tg * V_DIM + ti) * 64 + lane];
    float4v o4;
#pragma unroll
    for (int e2 = 0; e2 < 4; ++e2) o4[e2] = yv * c4[e2];
    ((float4v*)q)[(size_t)(m0 + trow) * 128 + tg * 64 + lane] = o4;
  }

  __syncthreads();
  const size_t pb = (size_t)(blockIdx.x & (NBUCKET - 1)) * GV;
  for (int e = tid; e < GV; e += 512) {
    atomicAdd(&mf[pb + e], accL[e]);
    atomicAdd(&mi[pb + e], cntL[e]);
  }
}

// ---------------- Finalize: sum 64 buckets, entropies, outputs ----------------
__global__ __launch_bounds__(640) void finalize_kernel(
    const float* __restrict__ mf, const int* __restrict__ mi,
    float* __restrict__ out3) {
  __shared__ float sA[G_DIM];
  __shared__ float sC[G_DIM];
  const int t = threadIdx.x;        // 0..639 == e
  if (t < G_DIM) { sA[t] = 0.0f; sC[t] = 0.0f; }
  __syncthreads();

  const int g = t / V_DIM;          // wave-uniform
  float f = 0.0f;
  int   c = 0;
#pragma unroll 8
  for (int b = 0; b < NBUCKET; ++b) {
    f += mf[(size_t)b * GV + t];
    c += mi[(size_t)b * GV + t];
  }
  const float pa = f * (1.0f / 16384.0f);
  const float ph = (float)c * (1.0f / 16384.0f);
  float a = pa * logf(pa + 1e-7f);
  float h = ph * logf(ph + 1e-7f);
#pragma unroll
  for (int off = 32; off > 0; off >>= 1) {
    a += __shfl_xor(a, off, 64);
    h += __shfl_xor(h, off, 64);
  }
  if ((t & 63) == 0) {
    atomicAdd(&sA[g], a);
    atomicAdd(&sC[g], h);
  }
  __syncthreads();
  if (t == 0) {
    const float code_p = expf(-sC[0]) + expf(-sC[1]);
    const float prob_p = expf(-sA[0]) + expf(-sA[1]);
    out3[0] = code_p;
    out3[1] = prob_p;
    out3[2] = ((float)GV - prob_p) / (float)GV;
  }
}

extern "C" void kernel_launch(void* const* d_in, const int* in_sizes, int n_in,
                              void* d_out, int out_size, void* d_ws, size_t ws_size,
                              hipStream_t stream) {
  const float* x  = (const float*)d_in[0];  // [8,2048,1024]
  const float* W  = (const float*)d_in[1];  // [640,1024]
  const float* b  = (const float*)d_in[2];  // [640]
  const float* cb = (const float*)d_in[3];  // [1,640,256]
  const float* gn = (const float*)d_in[4];  // [32768,320]
  float* out = (float*)d_out;               // q [16384*512] + 3 scalars

  char* ws = (char*)d_ws;
  _Float16* whT = (_Float16*)ws;             // 1,310,720 B
  float* mf = (float*)(ws + 1310720);        // 64*640*4 = 163,840 B
  int*   mi = (int*)  (ws + 1474560);        // 163,840 B

  // wsplit also zeroes mf+mi (327,680 B = 81,920 threads x 4 B)
  wsplit_kernel<<<(GV * C_DIM / 8) / 256, 256, 0, stream>>>(W, whT, (int*)mf);

  fused_kernel<<<FBLKS, 512, 0, stream>>>(x, whT, b, gn, cb, out, mf, mi);

  finalize_kernel<<<1, 640, 0, stream>>>(mf, mi, out + (size_t)N_ROWS * 512);
}